// Round 3
// baseline (1076.876 us; speedup 1.0000x reference)
//
#include <hip/hip_runtime.h>
#include <math.h>

#define NN 8192
#define SPARSE_WEIGHT 0.01f

// Native clang vector type: accepted by __builtin_nontemporal_load and
// lowers to global_load_dwordx4 (HIP's float4 is a struct — rejected).
typedef float floatx4 __attribute__((ext_vector_type(4)));

// Workspace layout (floats):
// ws[0] = sum_cos, ws[1] = sum_sin, ws[2] = sum_K2, ws[3] = sum_absK
// ws[4 .. 4+NN)      = sj[j] = alive[j]*sin(phases[j])
// ws[4+NN .. 4+2NN)  = cj[j] = alive[j]*cos(phases[j])

__device__ __forceinline__ float wave_reduce_sum(float v) {
#pragma unroll
    for (int off = 32; off > 0; off >>= 1)
        v += __shfl_down(v, off, 64);
    return v;
}

// Kernel A: per-element sin/cos prep + global sums of cos/sin for R.
__global__ __launch_bounds__(256) void prep_kernel(
        const float* __restrict__ phases,
        const float* __restrict__ alive,
        float* __restrict__ sj,
        float* __restrict__ cj,
        float* __restrict__ acc) {
    int j = blockIdx.x * blockDim.x + threadIdx.x;
    float s = 0.f, c = 0.f;
    if (j < NN) {
        float p = phases[j];
        s = sinf(p);
        c = cosf(p);
        float a = alive[j];
        sj[j] = a * s;
        cj[j] = a * c;
    }
    float ws = wave_reduce_sum(s);
    float wc = wave_reduce_sum(c);
    __shared__ float red_s[4], red_c[4];
    int lane = threadIdx.x & 63;
    int wave = threadIdx.x >> 6;
    if (lane == 0) { red_s[wave] = ws; red_c[wave] = wc; }
    __syncthreads();
    if (threadIdx.x == 0) {
        float bs = red_s[0] + red_s[1] + red_s[2] + red_s[3];
        float bc = red_c[0] + red_c[1] + red_c[2] + red_c[3];
        atomicAdd(&acc[1], bs);
        atomicAdd(&acc[0], bc);
    }
}

// Kernel B: one block per row i. Depth-2 software-pipelined stream of
// K-row + dist-row (nontemporal, single-use) + sj/cj (L2-resident).
// 8 dwordx4 loads in flight per wave -> MLP instead of serialized vmcnt(0).
__global__ __launch_bounds__(256) void row_kernel(
        const float* __restrict__ K,
        const float* __restrict__ dist,
        const float* __restrict__ sj,
        const float* __restrict__ cj,
        const float* __restrict__ phases,
        const float* __restrict__ alive,
        float* __restrict__ dtheta,   // points at out+1
        float* __restrict__ acc) {
    const int i = blockIdx.x;
    const floatx4* __restrict__ Kr = (const floatx4*)(K + (size_t)i * NN);
    const floatx4* __restrict__ Dr = (const floatx4*)(dist + (size_t)i * NN);
    const floatx4* __restrict__ S4 = (const floatx4*)sj;
    const floatx4* __restrict__ C4 = (const floatx4*)cj;

    float t1 = 0.f, t2 = 0.f, k2 = 0.f, ka = 0.f;

    int q = threadIdx.x;
    // Pipeline stage 0: issue iter-0 loads (K/dist first: longest latency).
    floatx4 k0 = __builtin_nontemporal_load(Kr + q);
    floatx4 d0 = __builtin_nontemporal_load(Dr + q);
    floatx4 s0 = S4[q];
    floatx4 c0 = C4[q];

#pragma unroll
    for (int it = 0; it < (NN / 4 / 256) - 1; ++it) {
        const int qn = q + 256;
        // Issue next iteration's loads into stage-1 regs BEFORE consuming stage-0.
        floatx4 k1 = __builtin_nontemporal_load(Kr + qn);
        floatx4 d1 = __builtin_nontemporal_load(Dr + qn);
        floatx4 s1 = S4[qn];
        floatx4 c1 = C4[qn];

        float km;
        km = k0.x * d0.x; t1 += km * s0.x; t2 += km * c0.x; k2 += k0.x * k0.x; ka += fabsf(k0.x);
        km = k0.y * d0.y; t1 += km * s0.y; t2 += km * c0.y; k2 += k0.y * k0.y; ka += fabsf(k0.y);
        km = k0.z * d0.z; t1 += km * s0.z; t2 += km * c0.z; k2 += k0.z * k0.z; ka += fabsf(k0.z);
        km = k0.w * d0.w; t1 += km * s0.w; t2 += km * c0.w; k2 += k0.w * k0.w; ka += fabsf(k0.w);

        k0 = k1; d0 = d1; s0 = s1; c0 = c1;
        q = qn;
    }
    // Epilogue: consume final stage.
    {
        float km;
        km = k0.x * d0.x; t1 += km * s0.x; t2 += km * c0.x; k2 += k0.x * k0.x; ka += fabsf(k0.x);
        km = k0.y * d0.y; t1 += km * s0.y; t2 += km * c0.y; k2 += k0.y * k0.y; ka += fabsf(k0.y);
        km = k0.z * d0.z; t1 += km * s0.z; t2 += km * c0.z; k2 += k0.z * k0.z; ka += fabsf(k0.z);
        km = k0.w * d0.w; t1 += km * s0.w; t2 += km * c0.w; k2 += k0.w * k0.w; ka += fabsf(k0.w);
    }

    t1 = wave_reduce_sum(t1);
    t2 = wave_reduce_sum(t2);
    k2 = wave_reduce_sum(k2);
    ka = wave_reduce_sum(ka);

    __shared__ float red[4][4];
    int lane = threadIdx.x & 63;
    int wave = threadIdx.x >> 6;
    if (lane == 0) { red[0][wave] = t1; red[1][wave] = t2; red[2][wave] = k2; red[3][wave] = ka; }
    __syncthreads();
    if (threadIdx.x == 0) {
        t1 = red[0][0] + red[0][1] + red[0][2] + red[0][3];
        t2 = red[1][0] + red[1][1] + red[1][2] + red[1][3];
        k2 = red[2][0] + red[2][1] + red[2][2] + red[2][3];
        ka = red[3][0] + red[3][1] + red[3][2] + red[3][3];
        float p = phases[i];
        dtheta[i] = alive[i] * (cosf(p) * t1 - sinf(p) * t2);
        atomicAdd(&acc[2], k2);
        atomicAdd(&acc[3], ka);
    }
}

// Kernel C: finalize scalars.
__global__ void finalize_kernel(const float* __restrict__ acc, float* __restrict__ out) {
    if (threadIdx.x == 0 && blockIdx.x == 0) {
        float cs = acc[0] / (float)NN;
        float ss = acc[1] / (float)NN;
        float R = sqrtf(cs * cs + ss * ss);
        out[0] = R;
        out[NN + 1] = 1.0f - R + 0.01f * sqrtf(acc[2]) + SPARSE_WEIGHT * acc[3];
    }
}

extern "C" void kernel_launch(void* const* d_in, const int* in_sizes, int n_in,
                              void* d_out, int out_size, void* d_ws, size_t ws_size,
                              hipStream_t stream) {
    const float* phases = (const float*)d_in[0];
    const float* alive  = (const float*)d_in[1];
    const float* dist   = (const float*)d_in[2];
    const float* K      = (const float*)d_in[3];
    float* out = (float*)d_out;
    float* ws  = (float*)d_ws;

    float* acc = ws;            // 4 floats
    float* sj  = ws + 4;        // NN floats (16B-aligned offset)
    float* cj  = ws + 4 + NN;   // NN floats (16B-aligned offset)

    (void)hipMemsetAsync(acc, 0, 4 * sizeof(float), stream);

    prep_kernel<<<NN / 256, 256, 0, stream>>>(phases, alive, sj, cj, acc);
    row_kernel<<<NN, 256, 0, stream>>>(K, dist, sj, cj, phases, alive, out + 1, acc);
    finalize_kernel<<<1, 64, 0, stream>>>(acc, out);
}

// Round 4
// 515.217 us; speedup vs baseline: 2.0901x; 2.0901x over previous
//
#include <hip/hip_runtime.h>
#include <math.h>

#define NN 8192
#define SPARSE_WEIGHT 0.01f

// Workspace layout (floats):
// ws[0] = sum_cos, ws[1] = sum_sin   (prep atomics, 32 blocks only)
// ws[4 .. 4+NN)        = sj[j] = alive[j]*sin(phases[j])
// ws[4+NN .. 4+2NN)    = cj[j] = alive[j]*cos(phases[j])
// ws[4+2NN .. 4+3NN)   = pk2[row]  per-block partial sum of K^2
// ws[4+3NN .. 4+4NN)   = pka[row]  per-block partial sum of |K|

__device__ __forceinline__ float wave_reduce_sum(float v) {
#pragma unroll
    for (int off = 32; off > 0; off >>= 1)
        v += __shfl_down(v, off, 64);
    return v;
}

// Kernel A: per-element sin/cos prep + global sums of cos/sin for R.
__global__ __launch_bounds__(256) void prep_kernel(
        const float* __restrict__ phases,
        const float* __restrict__ alive,
        float* __restrict__ sj,
        float* __restrict__ cj,
        float* __restrict__ acc) {
    int j = blockIdx.x * blockDim.x + threadIdx.x;
    float s = 0.f, c = 0.f;
    if (j < NN) {
        float p = phases[j];
        s = sinf(p);
        c = cosf(p);
        float a = alive[j];
        sj[j] = a * s;
        cj[j] = a * c;
    }
    float ws = wave_reduce_sum(s);
    float wc = wave_reduce_sum(c);
    __shared__ float red_s[4], red_c[4];
    int lane = threadIdx.x & 63;
    int wave = threadIdx.x >> 6;
    if (lane == 0) { red_s[wave] = ws; red_c[wave] = wc; }
    __syncthreads();
    if (threadIdx.x == 0) {
        float bs = red_s[0] + red_s[1] + red_s[2] + red_s[3];
        float bc = red_c[0] + red_c[1] + red_c[2] + red_c[3];
        atomicAdd(&acc[1], bs);
        atomicAdd(&acc[0], bc);
    }
}

// Kernel B: one block per row i. Stream K-row and dist-row once, fuse:
//   t1 = sum_j K*dist*sj[j],  t2 = sum_j K*dist*cj[j]
//   k2 = sum_j K*K,           ka = sum_j |K|
// dtheta[i] = alive[i] * (cos(p_i)*t1 - sin(p_i)*t2)
// NO atomics: k2/ka partials stored per block, reduced in kernel C.
__global__ __launch_bounds__(256) void row_kernel(
        const float* __restrict__ K,
        const float* __restrict__ dist,
        const float* __restrict__ sj,
        const float* __restrict__ cj,
        const float* __restrict__ phases,
        const float* __restrict__ alive,
        float* __restrict__ dtheta,   // points at out+1
        float* __restrict__ pk2,
        float* __restrict__ pka) {
    const int i = blockIdx.x;
    const float4* __restrict__ Kr = (const float4*)(K + (size_t)i * NN);
    const float4* __restrict__ Dr = (const float4*)(dist + (size_t)i * NN);
    const float4* __restrict__ S4 = (const float4*)sj;
    const float4* __restrict__ C4 = (const float4*)cj;

    float t1 = 0.f, t2 = 0.f, k2 = 0.f, ka = 0.f;
#pragma unroll 4
    for (int q = threadIdx.x; q < NN / 4; q += 256) {
        float4 k = Kr[q];
        float4 d = Dr[q];
        float4 s = S4[q];
        float4 c = C4[q];
        float km;
        km = k.x * d.x; t1 += km * s.x; t2 += km * c.x; k2 += k.x * k.x; ka += fabsf(k.x);
        km = k.y * d.y; t1 += km * s.y; t2 += km * c.y; k2 += k.y * k.y; ka += fabsf(k.y);
        km = k.z * d.z; t1 += km * s.z; t2 += km * c.z; k2 += k.z * k.z; ka += fabsf(k.z);
        km = k.w * d.w; t1 += km * s.w; t2 += km * c.w; k2 += k.w * k.w; ka += fabsf(k.w);
    }

    t1 = wave_reduce_sum(t1);
    t2 = wave_reduce_sum(t2);
    k2 = wave_reduce_sum(k2);
    ka = wave_reduce_sum(ka);

    __shared__ float red[4][4];
    int lane = threadIdx.x & 63;
    int wave = threadIdx.x >> 6;
    if (lane == 0) { red[0][wave] = t1; red[1][wave] = t2; red[2][wave] = k2; red[3][wave] = ka; }
    __syncthreads();
    if (threadIdx.x == 0) {
        t1 = red[0][0] + red[0][1] + red[0][2] + red[0][3];
        t2 = red[1][0] + red[1][1] + red[1][2] + red[1][3];
        k2 = red[2][0] + red[2][1] + red[2][2] + red[2][3];
        ka = red[3][0] + red[3][1] + red[3][2] + red[3][3];
        float p = phases[i];
        dtheta[i] = alive[i] * (cosf(p) * t1 - sinf(p) * t2);
        pk2[i] = k2;    // plain store — no atomic
        pka[i] = ka;
    }
}

// Kernel C: reduce the 8192 per-block partials + finalize scalars.
// Single block, 1024 threads (16 waves).
__global__ __launch_bounds__(1024) void finalize_kernel(
        const float* __restrict__ acc,
        const float* __restrict__ pk2,
        const float* __restrict__ pka,
        float* __restrict__ out) {
    float k2 = 0.f, ka = 0.f;
    for (int j = threadIdx.x; j < NN; j += 1024) {
        k2 += pk2[j];
        ka += pka[j];
    }
    k2 = wave_reduce_sum(k2);
    ka = wave_reduce_sum(ka);
    __shared__ float rk2[16], rka[16];
    int lane = threadIdx.x & 63;
    int wave = threadIdx.x >> 6;
    if (lane == 0) { rk2[wave] = k2; rka[wave] = ka; }
    __syncthreads();
    if (threadIdx.x == 0) {
        float sk2 = 0.f, ska = 0.f;
#pragma unroll
        for (int w = 0; w < 16; ++w) { sk2 += rk2[w]; ska += rka[w]; }
        float cs = acc[0] / (float)NN;
        float ss = acc[1] / (float)NN;
        float R = sqrtf(cs * cs + ss * ss);
        out[0] = R;
        out[NN + 1] = 1.0f - R + 0.01f * sqrtf(sk2) + SPARSE_WEIGHT * ska;
    }
}

extern "C" void kernel_launch(void* const* d_in, const int* in_sizes, int n_in,
                              void* d_out, int out_size, void* d_ws, size_t ws_size,
                              hipStream_t stream) {
    const float* phases = (const float*)d_in[0];
    const float* alive  = (const float*)d_in[1];
    const float* dist   = (const float*)d_in[2];
    const float* K      = (const float*)d_in[3];
    float* out = (float*)d_out;
    float* ws  = (float*)d_ws;

    float* acc = ws;                 // 4 floats (0,1 used)
    float* sj  = ws + 4;             // NN floats
    float* cj  = ws + 4 + NN;        // NN floats
    float* pk2 = ws + 4 + 2 * NN;    // NN floats
    float* pka = ws + 4 + 3 * NN;    // NN floats

    (void)hipMemsetAsync(acc, 0, 4 * sizeof(float), stream);

    prep_kernel<<<NN / 256, 256, 0, stream>>>(phases, alive, sj, cj, acc);
    row_kernel<<<NN, 256, 0, stream>>>(K, dist, sj, cj, phases, alive, out + 1, pk2, pka);
    finalize_kernel<<<1, 1024, 0, stream>>>(acc, pk2, pka, out);
}